// Round 6
// baseline (178.100 us; speedup 1.0000x reference)
//
#include <hip/hip_runtime.h>
#include <hip/hip_bf16.h>

// FuzzyContrastiveLearning: loss = mean_i[ -log(pos_i / (all_i + eps)) ]
// Symmetric Gram, triangular 256^2 tiles (528), persistent grid (512).
// Branch-free 8-phase K-loop (tails peeled), counted vmcnt(8), T2 XOR swizzle,
// T5 setprio, cross-tile prologue staging hidden under LDS-free epilogue.

#define NROWS 8192
#define DIM   768
#define BM    256
#define BK    64
#define NKT   (DIM / BK)               // 12
#define NBLK  (NROWS / BM)             // 32
#define NTILES (NBLK * (NBLK + 1) / 2) // 528
#define GRID  512
#define L2E   1.4426950408889634f

typedef __attribute__((ext_vector_type(8))) short short8;
typedef __attribute__((ext_vector_type(4))) float f32x4;

__device__ __forceinline__ void gload_lds16(const void* g, void* l) {
  __builtin_amdgcn_global_load_lds(
      (const __attribute__((address_space(1))) void*)g,
      (__attribute__((address_space(3))) void*)l, 16, 0, 0);
}

// triangular decode with bijective XCD-chunk swizzle (NTILES % 8 == 0)
__device__ __forceinline__ void decode_tile(int w, int& bi, int& bj) {
  const int t = (w & 7) * (NTILES / 8) + (w >> 3);
  int b = (int)(((double)(2 * NBLK + 1) -
                 sqrt((double)(2 * NBLK + 1) * (2 * NBLK + 1) - 8.0 * t)) * 0.5);
  while ((b + 1) * (2 * NBLK - b) / 2 <= t) ++b;
  while (b * (2 * NBLK - b + 1) / 2 > t) --b;
  bi = b;
  bj = b + (t - b * (2 * NBLK - b + 1) / 2);
}

// Kernel 1: fp32 -> bf16 + row norms of bf16-rounded values; first 16 blocks
// also zero the (pos,all) atomic accumulators.
__global__ void prep_kernel(const float* __restrict__ x,
                            ushort* __restrict__ xb,
                            float* __restrict__ norms,
                            float* __restrict__ part) {
  if (blockIdx.x < 16)
    ((float4*)part)[blockIdx.x * 256 + threadIdx.x] = make_float4(0.f, 0.f, 0.f, 0.f);
  const int row  = blockIdx.x * 4 + (threadIdx.x >> 6);
  const int lane = threadIdx.x & 63;
  const float4* xr = (const float4*)(x + (size_t)row * DIM);
  ushort4* xbr = (ushort4*)(xb + (size_t)row * DIM);
  float acc = 0.f;
  #pragma unroll
  for (int c = 0; c < DIM / 4 / 64; ++c) {   // 3
    float4 v = xr[c * 64 + lane];
    union { __hip_bfloat16 b; ushort u; } cv;
    ushort4 o;
    cv.b = __float2bfloat16(v.x); o.x = cv.u; float f0 = __bfloat162float(cv.b);
    cv.b = __float2bfloat16(v.y); o.y = cv.u; float f1 = __bfloat162float(cv.b);
    cv.b = __float2bfloat16(v.z); o.z = cv.u; float f2 = __bfloat162float(cv.b);
    cv.b = __float2bfloat16(v.w); o.w = cv.u; float f3 = __bfloat162float(cv.b);
    acc += f0 * f0 + f1 * f1 + f2 * f2 + f3 * f3;
    xbr[c * 64 + lane] = o;
  }
  #pragma unroll
  for (int off = 32; off; off >>= 1) acc += __shfl_down(acc, off);
  if (lane == 0) norms[row] = acc;
}

// Kernel 2: persistent blocks; 256x256 upper-triangle tiles. 512 thr = 8 waves.
__global__ __launch_bounds__(512, 2)
void fused_kernel(const ushort* __restrict__ xb,
                  const float* __restrict__ norms,
                  const int* __restrict__ labels,
                  float* __restrict__ part) {  // part[2*row]=pos, [2*row+1]=all
  __shared__ ushort sh[65536];   // 128 KiB: [A/B][dbuf][half][128*64]
  #define SH(ab, P, h) (sh + ((((ab) * 2 + (P)) * 2 + (h)) * 8192))

  const int tid  = threadIdx.x;
  const int lane = tid & 63;
  const int wid  = tid >> 6;        // 0..7
  const int wm   = wid >> 2;        // 0,1  -> rows wm*128..
  const int wvn  = wid & 3;         // 0..3 -> cols wvn*64..
  const int ln15 = lane & 15, hi4 = lane >> 4;
  const int slotx = ln15 & 7;
  const int brow7 = (wvn & 1) * 64;

  // staging geometry: LDS dest linear (wave-uniform base + lane*16B),
  // global source slot XOR'd by row (T2; verified conflict-free R2-R5).
  const int c0 = tid, c1 = 512 + tid;
  const int r0 = c0 >> 3, r1 = c1 >> 3;
  const size_t gao0 = (size_t)r0 * DIM + ((c0 & 7) ^ (r0 & 7)) * 8;
  const size_t gao1 = (size_t)r1 * DIM + ((c1 & 7) ^ (r1 & 7)) * 8;
  const int d0 = c0 * 8, d1 = c1 * 8;

  #define STAGEH(gbase, ab, h, P, ktv) do {                                \
      const ushort* _g = (gbase) + (size_t)(h) * 128 * DIM + (ktv) * BK;   \
      ushort* _l = SH(ab, P, h);                                           \
      gload_lds16(_g + gao0, _l + d0);                                     \
      gload_lds16(_g + gao1, _l + d1);                                     \
    } while (0)

  #define READ_A(mibase)                                                   \
    _Pragma("unroll")                                                      \
    for (int mi = 0; mi < 4; ++mi)                                         \
      _Pragma("unroll")                                                    \
      for (int kk = 0; kk < 2; ++kk)                                       \
        aR[mi][kk] = *(const short8*)&Ab[((mibase + mi) * 16 + ln15) * 64 +  \
                                         ((((kk << 2) | hi4) ^ slotx) << 3)];
  #define READ_B(njbase)                                                   \
    _Pragma("unroll")                                                      \
    for (int nq = 0; nq < 2; ++nq)                                         \
      _Pragma("unroll")                                                    \
      for (int kk = 0; kk < 2; ++kk)                                       \
        bR[njbase + nq][kk] = *(const short8*)&Bb[(brow7 + (njbase + nq) * 16 + ln15) * 64 + \
                                                  ((((kk << 2) | hi4) ^ slotx) << 3)];
  #define QUAD(mibase, njbase)                                             \
    __builtin_amdgcn_s_setprio(1);                                         \
    _Pragma("unroll")                                                      \
    for (int mi = 0; mi < 4; ++mi)                                         \
      _Pragma("unroll")                                                    \
      for (int nq = 0; nq < 2; ++nq)                                       \
        _Pragma("unroll")                                                  \
        for (int kk = 0; kk < 2; ++kk)                                     \
          acc[mibase + mi][njbase + nq] = __builtin_amdgcn_mfma_f32_16x16x32_bf16( \
              aR[mi][kk], bR[njbase + nq][kk], acc[mibase + mi][njbase + nq], 0, 0, 0); \
    __builtin_amdgcn_s_setprio(0);

  #define BAR   __builtin_amdgcn_s_barrier()
  #define LGKM0 do { asm volatile("s_waitcnt lgkmcnt(0)");                 \
                     __builtin_amdgcn_sched_barrier(0); } while (0)

  // steady phase-group: 4 phases of one K-tile; stages kt+2 (branch-free)
  #define STEP(P, ktv) do {                                                \
      const ushort* Ab = SH(0, P, wm);                                     \
      const ushort* Bb = SH(1, P, wvn >> 1);                               \
      short8 aR[4][2], bR[4][2];                                           \
      READ_A(0); READ_B(0);                                                \
      BAR; LGKM0; QUAD(0, 0); BAR;                                         \
      READ_B(2);                                                           \
      BAR; LGKM0; QUAD(0, 2); BAR;                                         \
      READ_A(4);                                                           \
      STAGEH(gB, 1, 0, P, (ktv) + 2); STAGEH(gB, 1, 1, P, (ktv) + 2);      \
      BAR; LGKM0; QUAD(4, 2); BAR;                                         \
      STAGEH(gA, 0, 0, P, (ktv) + 2); STAGEH(gA, 0, 1, P, (ktv) + 2);      \
      BAR; QUAD(4, 0);                                                     \
      asm volatile("s_waitcnt vmcnt(8)");                                  \
      __builtin_amdgcn_sched_barrier(0);                                   \
      BAR;                                                                 \
    } while (0)

  // tail variants: no staging; T1 drains remaining loads, T2 plain
  #define STEP_TAIL(P, VM) do {                                            \
      const ushort* Ab = SH(0, P, wm);                                     \
      const ushort* Bb = SH(1, P, wvn >> 1);                               \
      short8 aR[4][2], bR[4][2];                                           \
      READ_A(0); READ_B(0);                                                \
      BAR; LGKM0; QUAD(0, 0); BAR;                                         \
      READ_B(2);                                                           \
      BAR; LGKM0; QUAD(0, 2); BAR;                                         \
      READ_A(4);                                                           \
      BAR; LGKM0; QUAD(4, 2); BAR;                                         \
      BAR; QUAD(4, 0);                                                     \
      if (VM) { asm volatile("s_waitcnt vmcnt(0)");                        \
                __builtin_amdgcn_sched_barrier(0); }                       \
      BAR;                                                                 \
    } while (0)

  int w = blockIdx.x;          // GRID <= NTILES: every block has >=1 tile
  int bi, bj;
  decode_tile(w, bi, bj);
  const ushort* gA = xb + (size_t)bi * BM * DIM;
  const ushort* gB = xb + (size_t)bj * BM * DIM;

  // first tile: stage kt0 (parity 0) + kt1 (parity 1)
  STAGEH(gA, 0, 0, 0, 0); STAGEH(gA, 0, 1, 0, 0);
  STAGEH(gB, 1, 0, 0, 0); STAGEH(gB, 1, 1, 0, 0);
  STAGEH(gA, 0, 0, 1, 1); STAGEH(gA, 0, 1, 1, 1);
  STAGEH(gB, 1, 0, 1, 1); STAGEH(gB, 1, 1, 1, 1);

  while (true) {
    asm volatile("s_waitcnt vmcnt(8)");    // kt0 landed; kt1's 8 in flight
    __builtin_amdgcn_sched_barrier(0);
    BAR;

    f32x4 zero = {0.f, 0.f, 0.f, 0.f};
    f32x4 acc[8][4];
    #pragma unroll
    for (int mi = 0; mi < 8; ++mi)
      #pragma unroll
      for (int nj = 0; nj < 4; ++nj) acc[mi][nj] = zero;

    #pragma unroll 1
    for (int kt = 0; kt < NKT - 2; kt += 2) {   // kt = 0,2,4,6,8
      STEP(0, kt);
      STEP(1, kt + 1);
    }
    STEP_TAIL(0, 1);   // kt = 10: drain kt11's loads at the end
    STEP_TAIL(1, 0);   // kt = 11

    // ---- issue next tile's prologue staging (hidden under epilogue) ----
    const int wnext = w + GRID;
    const bool have_next = (wnext < NTILES);
    int nbi = bi, nbj = bj;
    const ushort *ngA = gA, *ngB = gB;
    if (have_next) {
      decode_tile(wnext, nbi, nbj);
      ngA = xb + (size_t)nbi * BM * DIM;
      ngB = xb + (size_t)nbj * BM * DIM;
      STAGEH(ngA, 0, 0, 0, 0); STAGEH(ngA, 0, 1, 0, 0);
      STAGEH(ngB, 1, 0, 0, 0); STAGEH(ngB, 1, 1, 0, 0);
      STAGEH(ngA, 0, 0, 1, 1); STAGEH(ngA, 0, 1, 1, 1);
      STAGEH(ngB, 1, 0, 1, 1); STAGEH(ngB, 1, 1, 1, 1);
    }

    // ---- LDS-free epilogue: exp + split sums + shfl reduce + atomics ----
    const int brow = bi * BM, bcol = bj * BM;
    const bool diag = (bi == bj);

    float hj2neg[4], fc1[4], fc0[4];
    int lc[4];
    #pragma unroll
    for (int nj = 0; nj < 4; ++nj) {
      int col = bcol + wvn * 64 + nj * 16 + ln15;
      hj2neg[nj] = -0.5f * L2E * norms[col];
      lc[nj] = labels[col];
      fc1[nj] = (float)lc[nj]; fc0[nj] = 1.0f - fc1[nj];
    }
    float cs0[4] = {0.f, 0.f, 0.f, 0.f}, cs1[4] = {0.f, 0.f, 0.f, 0.f};

    #pragma unroll
    for (int mi = 0; mi < 8; ++mi) {
      const int rbase = brow + wm * 128 + mi * 16 + hi4 * 4;
      const float4 nv = *(const float4*)&norms[rbase];
      const int4  lv = *(const int4*)&labels[rbase];
      float hi2neg[4] = { -0.5f * L2E * nv.x, -0.5f * L2E * nv.y,
                          -0.5f * L2E * nv.z, -0.5f * L2E * nv.w };
      float lr1[4] = { (float)lv.x, (float)lv.y, (float)lv.z, (float)lv.w };
      float hmax = fmaxf(fmaxf(hi2neg[0], hi2neg[1]), fmaxf(hi2neg[2], hi2neg[3]));
      float rs0[4] = {0.f, 0.f, 0.f, 0.f}, rs1[4] = {0.f, 0.f, 0.f, 0.f};
      #pragma unroll
      for (int nj = 0; nj < 4; ++nj) {
        f32x4 a = acc[mi][nj];
        float vmax = fmaxf(fmaxf(a[0], a[1]), fmaxf(a[2], a[3]));
        float tmax = fmaf(vmax, L2E, hmax) + hj2neg[nj];
        if (tmax > -30.f) {   // else all f underflow to 0.0f exactly
          #pragma unroll
          for (int r = 0; r < 4; ++r) {
            float tt = fmaf(a[r], L2E, hi2neg[r]) + hj2neg[nj];
            float f = __builtin_amdgcn_exp2f(tt);
            rs1[r] = fmaf(f, fc1[nj], rs1[r]);       // row-sum, by COL label
            rs0[r] = fmaf(f, fc0[nj], rs0[r]);
            cs1[nj] = fmaf(f, lr1[r], cs1[nj]);      // col-sum, by ROW label
            cs0[nj] = fmaf(f, 1.0f - lr1[r], cs0[nj]);
          }
        }
      }
      // reduce rows over the 16 ln15 lanes; direct atomics (4-way wvn contention)
      #pragma unroll
      for (int r = 0; r < 4; ++r) {
        float a = rs0[r], b = rs1[r];
        #pragma unroll
        for (int off = 1; off < 16; off <<= 1) {
          a += __shfl_xor(a, off);
          b += __shfl_xor(b, off);
        }
        if (ln15 == 0) {
          float pos = (lr1[r] != 0.f) ? b : a;
          atomicAdd(&part[2 * (rbase + r) + 0], pos);
          atomicAdd(&part[2 * (rbase + r) + 1], a + b);
        }
      }
    }

    if (!diag) {   // transpose contribution f(j,i) to rows of block bj
      #pragma unroll
      for (int nj = 0; nj < 4; ++nj) {
        float a = cs0[nj], b = cs1[nj];
        a += __shfl_xor(a, 16); a += __shfl_xor(a, 32);
        b += __shfl_xor(b, 16); b += __shfl_xor(b, 32);
        if (hi4 == 0) {
          int col = bcol + wvn * 64 + nj * 16 + ln15;
          float pos = lc[nj] ? b : a;
          atomicAdd(&part[2 * col + 0], pos);
          atomicAdd(&part[2 * col + 1], a + b);
        }
      }
    }

    if (!have_next) break;
    w = wnext; bi = nbi; bj = nbj; gA = ngA; gB = ngB;
  }
}

// Kernel 3: per-row loss + mean.
__global__ void loss_kernel(const float* __restrict__ part,
                            float* __restrict__ out) {
  int tid = threadIdx.x;  // 1024
  float sum = 0.f;
  for (int row = tid; row < NROWS; row += 1024) {
    float pos = part[2 * row], all = part[2 * row + 1];
    sum += -logf(pos / (all + 1e-8f));
  }
  for (int off = 32; off; off >>= 1) sum += __shfl_down(sum, off);
  __shared__ float w[16];
  if ((tid & 63) == 0) w[tid >> 6] = sum;
  __syncthreads();
  if (tid == 0) {
    float t = 0.f;
    for (int i = 0; i < 16; ++i) t += w[i];
    out[0] = t / (float)NROWS;
  }
}

extern "C" void kernel_launch(void* const* d_in, const int* in_sizes, int n_in,
                              void* d_out, int out_size, void* d_ws, size_t ws_size,
                              hipStream_t stream) {
  const float* x      = (const float*)d_in[0];
  const int*   labels = (const int*)d_in[1];
  char* ws = (char*)d_ws;

  const size_t xb_bytes    = (size_t)NROWS * DIM * 2;   // 12,582,912
  const size_t norms_bytes = (size_t)NROWS * 4;         // 32,768
  const size_t part_bytes  = (size_t)NROWS * 2 * 4;     // 65,536
  if (ws_size < xb_bytes + norms_bytes + part_bytes) return;

  ushort* xb    = (ushort*)ws;
  float*  norms = (float*)(ws + xb_bytes);
  float*  part  = (float*)(ws + xb_bytes + norms_bytes);

  prep_kernel<<<NROWS / 4, 256, 0, stream>>>(x, xb, norms, part);
  fused_kernel<<<GRID, 512, 0, stream>>>(xb, norms, labels, part);
  loss_kernel<<<1, 1024, 0, stream>>>(part, (float*)d_out);
}